// Round 5
// baseline (984.939 us; speedup 1.0000x reference)
//
#include <hip/hip_runtime.h>
#include <math.h>

#define NN 100000
#define NE 1600000
#define HID 512
#define NCLS 393

// ---------------- CSR build ----------------
__global__ void k_count(const int* __restrict__ dst, int* __restrict__ cnt) {
    int e = blockIdx.x * 256 + threadIdx.x;
    if (e < NE) atomicAdd(&cnt[dst[e]], 1);
}

// dinv = rsqrt(1+cnt); off = bump-alloc (disjoint contiguous ranges form a valid CSR); cur = 0
__global__ void k_off(const int* __restrict__ cnt, float* __restrict__ dinv,
                      int* __restrict__ off, int* __restrict__ cur, int* __restrict__ gtot) {
    int i = blockIdx.x * 256 + threadIdx.x;
    if (i < NN) {
        int c = cnt[i];
        dinv[i] = rsqrtf(1.0f + (float)c);
        off[i] = atomicAdd(gtot, c);
        cur[i] = 0;
    }
}

// pack (src, norm) into int2 so gather does one 8B load per edge
__global__ void k_fill(const int* __restrict__ src, const int* __restrict__ dst,
                       const float* __restrict__ dinv, const int* __restrict__ off,
                       int* __restrict__ cur, int2* __restrict__ epack) {
    int e = blockIdx.x * 256 + threadIdx.x;
    if (e < NE) {
        int s = src[e], d = dst[e];
        int pos = off[d] + atomicAdd(&cur[d], 1);
        epack[pos] = make_int2(s, __float_as_int(dinv[s] * dinv[d]));
    }
}

// ---------------- row GEMM: out = act(x) @ W (+bout) ----------------
template<bool IN_ACT, bool OUT_BIAS>
__global__ void k_gemm64b(const float* __restrict__ x, const float* __restrict__ W,
                          const float* __restrict__ bin, const float* __restrict__ bout,
                          float* __restrict__ out) {
    __shared__ float Ws[64 * 64];
    __shared__ float xs[32 * 64];
    int tid = threadIdx.x;
    size_t n0 = (size_t)blockIdx.x * 32;
    for (int i = tid; i < 1024; i += 256)
        ((float4*)Ws)[i] = ((const float4*)W)[i];
    for (int i = tid; i < 512; i += 256) {
        float4 v = ((const float4*)(x + n0 * 64))[i];
        if (IN_ACT) {
            int c = (i & 15) * 4;
            float4 bv = *(const float4*)(bin + c);
            v.x = fmaxf(v.x + bv.x, 0.f);
            v.y = fmaxf(v.y + bv.y, 0.f);
            v.z = fmaxf(v.z + bv.z, 0.f);
            v.w = fmaxf(v.w + bv.w, 0.f);
        }
        ((float4*)xs)[i] = v;
    }
    __syncthreads();
    int j = tid & 63, q = tid >> 6;
    float Wreg[64];
#pragma unroll
    for (int k = 0; k < 64; ++k) Wreg[k] = Ws[k * 64 + j];
    float bo = OUT_BIAS ? bout[j] : 0.f;
    for (int r = 0; r < 8; ++r) {
        int row = q * 8 + r;
        float accA = bo, accB = 0.f;
        const float4* xr = (const float4*)(xs + row * 64);
#pragma unroll
        for (int k4 = 0; k4 < 16; k4 += 2) {
            float4 x0 = xr[k4], x1 = xr[k4 + 1];
            accA = fmaf(x0.x, Wreg[k4 * 4 + 0], accA);
            accA = fmaf(x0.y, Wreg[k4 * 4 + 1], accA);
            accA = fmaf(x0.z, Wreg[k4 * 4 + 2], accA);
            accA = fmaf(x0.w, Wreg[k4 * 4 + 3], accA);
            accB = fmaf(x1.x, Wreg[k4 * 4 + 4], accB);
            accB = fmaf(x1.y, Wreg[k4 * 4 + 5], accB);
            accB = fmaf(x1.z, Wreg[k4 * 4 + 6], accB);
            accB = fmaf(x1.w, Wreg[k4 * 4 + 7], accB);
        }
        out[(n0 + row) * 64 + j] = accA + accB;
    }
}

// ---------------- CSR gather: one wave/node; 8 edges x 8 lanes x 2*float4 ----------------
__global__ void k_gather3(const int2* __restrict__ epack, const int* __restrict__ off,
                          const int* __restrict__ cnt, const float* __restrict__ dinv,
                          const float* __restrict__ t, float* __restrict__ out) {
    int lane = threadIdx.x & 63;
    int n = (blockIdx.x * 256 + threadIdx.x) >> 6;
    if (n >= NN) return;
    int g = lane >> 3, fl = lane & 7;
    int o = off[n], c = cnt[n];
    float4 a0 = {0.f, 0.f, 0.f, 0.f}, a1 = {0.f, 0.f, 0.f, 0.f};
    if (c > 0) {
        for (int b = 0; b < c; b += 8) {
            int idx = b + g;
            int2 ep = epack[o + min(idx, c - 1)];  // 8-lane broadcast, clamped
            float w = (idx < c) ? __int_as_float(ep.y) : 0.f;
            const float* row = t + (size_t)ep.x * 64 + fl * 8;
            float4 v0 = *(const float4*)row;
            float4 v1 = *(const float4*)(row + 4);
            a0.x = fmaf(v0.x, w, a0.x);
            a0.y = fmaf(v0.y, w, a0.y);
            a0.z = fmaf(v0.z, w, a0.z);
            a0.w = fmaf(v0.w, w, a0.w);
            a1.x = fmaf(v1.x, w, a1.x);
            a1.y = fmaf(v1.y, w, a1.y);
            a1.z = fmaf(v1.z, w, a1.z);
            a1.w = fmaf(v1.w, w, a1.w);
        }
    }
#pragma unroll
    for (int m = 8; m <= 32; m <<= 1) {
        a0.x += __shfl_xor(a0.x, m); a0.y += __shfl_xor(a0.y, m);
        a0.z += __shfl_xor(a0.z, m); a0.w += __shfl_xor(a0.w, m);
        a1.x += __shfl_xor(a1.x, m); a1.y += __shfl_xor(a1.y, m);
        a1.z += __shfl_xor(a1.z, m); a1.w += __shfl_xor(a1.w, m);
    }
    if (lane < 8) {
        float dv = dinv[n];
        float d2 = dv * dv;
        const float* srow = t + (size_t)n * 64 + fl * 8;
        float4 s0 = *(const float4*)srow;
        float4 s1 = *(const float4*)(srow + 4);
        float4 r0, r1;
        r0.x = a0.x + s0.x * d2; r0.y = a0.y + s0.y * d2;
        r0.z = a0.z + s0.z * d2; r0.w = a0.w + s0.w * d2;
        r1.x = a1.x + s1.x * d2; r1.y = a1.y + s1.y * d2;
        r1.z = a1.z + s1.z * d2; r1.w = a1.w + s1.w * d2;
        float* orow = out + (size_t)n * 64 + fl * 8;
        *(float4*)orow = r0;
        *(float4*)(orow + 4) = r1;
    }
}

// ---------------- transpose GEMM, split-K, padded uniform inner loop ----------------
#define TG_SPLIT 261
#define TG_CHUNK 384  // 6 stages of 64; 261*384 = 100224 >= 100000
__global__ void k_tgemm4(const float* __restrict__ scores, const float* __restrict__ W4,
                         float* __restrict__ Pp) {
    __shared__ float ss[64 * 64];
    int colT = blockIdx.x & 3;
    int kc = blockIdx.x >> 2;
    int tid = threadIdx.x;
    int tc = tid & 31, tr = tid >> 5;
    int col = colT * 128 + tc * 4;
    float acc[8][4];
#pragma unroll
    for (int i = 0; i < 8; ++i)
#pragma unroll
        for (int c = 0; c < 4; ++c) acc[i][c] = 0.f;
    int k0 = kc * TG_CHUNK;
    for (int st = 0; st < 6; ++st) {
        int kb = k0 + st * 64;
        __syncthreads();
        for (int i = tid; i < 1024; i += 256) {
            float4 v = {0.f, 0.f, 0.f, 0.f};
            if (kb + (i >> 4) < NN) v = ((const float4*)(scores + (size_t)kb * 64))[i];
            ((float4*)ss)[i] = v;
        }
        __syncthreads();
        for (int nIt = 0; nIt < 64; nIt += 4) {
            float4 w[4];
#pragma unroll
            for (int u = 0; u < 4; ++u) {
                int row = min(kb + nIt + u, NN - 1);  // clamped; padded s=0 kills contribution
                w[u] = *(const float4*)(W4 + (size_t)row * 512 + col);
            }
#pragma unroll
            for (int u = 0; u < 4; ++u) {
                const float4* sp = (const float4*)(ss + (nIt + u) * 64 + tr * 8);
                float4 s0 = sp[0], s1 = sp[1];
                float sa[8] = {s0.x, s0.y, s0.z, s0.w, s1.x, s1.y, s1.z, s1.w};
#pragma unroll
                for (int i = 0; i < 8; ++i) {
                    acc[i][0] = fmaf(sa[i], w[u].x, acc[i][0]);
                    acc[i][1] = fmaf(sa[i], w[u].y, acc[i][1]);
                    acc[i][2] = fmaf(sa[i], w[u].z, acc[i][2]);
                    acc[i][3] = fmaf(sa[i], w[u].w, acc[i][3]);
                }
            }
        }
    }
    float* pb = Pp + (size_t)kc * 64 * 512;
#pragma unroll
    for (int i = 0; i < 8; ++i) {
        int row = tr * 8 + i;
        *(float4*)(pb + row * 512 + col) = make_float4(acc[i][0], acc[i][1], acc[i][2], acc[i][3]);
    }
}

// ---------------- reduce partials: P[o] = sum_kc Pp[kc][o], 512 blocks ----------------
__global__ void k_reduce2(const float* __restrict__ Pp, float* __restrict__ P) {
    __shared__ float red[256];
    int tid = threadIdx.x;
    int o = blockIdx.x * 64 + (tid & 63);
    int q = tid >> 6;
    int k0 = q * 66, k1 = min(k0 + 66, TG_SPLIT);
    float s = 0.f;
    for (int kc = k0; kc < k1; ++kc) s += Pp[(size_t)kc * 32768 + o];
    red[tid] = s;
    __syncthreads();
    if (tid < 64) P[o] = red[tid] + red[tid + 64] + red[tid + 128] + red[tid + 192];
}

// ---------------- final: logits = relu(P+b4) @ W5 + b5; log_softmax rows ----------------
__global__ void k_final(const float* __restrict__ P, const float* __restrict__ b4,
                        const float* __restrict__ W5, const float* __restrict__ b5,
                        float* __restrict__ out) {
    __shared__ float p[HID];
    __shared__ float z[NCLS];
    __shared__ float red[256];
    int i = blockIdx.x;
    int tid = threadIdx.x;
    for (int k = tid; k < HID; k += 256) p[k] = fmaxf(P[i * HID + k] + b4[k], 0.f);
    __syncthreads();
    for (int c = tid; c < NCLS; c += 256) {
        float acc = b5[c];
        for (int k = 0; k < HID; ++k) acc = fmaf(p[k], W5[(size_t)k * NCLS + c], acc);
        z[c] = acc;
    }
    __syncthreads();
    float m = -INFINITY;
    for (int c = tid; c < NCLS; c += 256) m = fmaxf(m, z[c]);
    red[tid] = m;
    __syncthreads();
    for (int s = 128; s > 0; s >>= 1) {
        if (tid < s) red[tid] = fmaxf(red[tid], red[tid + s]);
        __syncthreads();
    }
    m = red[0];
    __syncthreads();
    float sum = 0.f;
    for (int c = tid; c < NCLS; c += 256) sum += expf(z[c] - m);
    red[tid] = sum;
    __syncthreads();
    for (int s = 128; s > 0; s >>= 1) {
        if (tid < s) red[tid] += red[tid + s];
        __syncthreads();
    }
    float lse = m + logf(red[0]);
    for (int c = tid; c < NCLS; c += 256) out[i * NCLS + c] = z[c] - lse;
}

extern "C" void kernel_launch(void* const* d_in, const int* in_sizes, int n_in,
                              void* d_out, int out_size, void* d_ws, size_t ws_size,
                              hipStream_t stream) {
    const int* adj = (const int*)d_in[0];
    const int* src = adj;
    const int* dst = adj + NE;
    const float* feat = (const float*)d_in[1];
    const float* W1 = (const float*)d_in[2];
    const float* b1 = (const float*)d_in[3];
    const float* W2 = (const float*)d_in[4];
    const float* b2 = (const float*)d_in[5];
    const float* W3 = (const float*)d_in[6];
    const float* b3 = (const float*)d_in[7];
    const float* Wlin = (const float*)d_in[8];
    const float* blin = (const float*)d_in[9];
    const float* W4 = (const float*)d_in[10];
    const float* b4 = (const float*)d_in[11];
    const float* W5 = (const float*)d_in[12];
    const float* b5 = (const float*)d_in[13];
    float* out = (float*)d_out;

    // layout: cnt|gtot adjacent (single memset); bufB|epack adjacent (Pp alias, 38.4MB)
    char* ws = (char*)d_ws;
    int*   cnt   = (int*)ws;    ws += (size_t)NN * 4;
    int*   gtot  = (int*)ws;    ws += 16;
    float* dinv  = (float*)ws;  ws += (size_t)NN * 4;
    int*   off   = (int*)ws;    ws += (size_t)NN * 4;
    int*   cur   = (int*)ws;    ws += (size_t)NN * 4;
    float* bufA  = (float*)ws;  ws += (size_t)NN * 64 * 4;
    float* bufB  = (float*)ws;  ws += (size_t)NN * 64 * 4;
    int2*  epack = (int2*)ws;   ws += (size_t)NE * 8;
    float* P     = (float*)ws;  ws += 64 * HID * 4;

    const int NB_N = (NN + 255) / 256;
    const int NB_E = NE / 256;
    const int NB_G = NN / 32;
    const int NB_GA = NN / 4;
    const int NB_T = 4 * TG_SPLIT;  // 1044

    // CSR + degree norm
    hipMemsetAsync(cnt, 0, (size_t)NN * 4 + 16, stream);  // cnt + gtot
    k_count<<<NB_E, 256, 0, stream>>>(dst, cnt);
    k_off<<<NB_N, 256, 0, stream>>>(cnt, dinv, off, cur, gtot);
    k_fill<<<NB_E, 256, 0, stream>>>(src, dst, dinv, off, cur, epack);

    // layer 1
    k_gemm64b<false, false><<<NB_G, 256, 0, stream>>>(feat, W1, nullptr, nullptr, bufA);
    k_gather3<<<NB_GA, 256, 0, stream>>>(epack, off, cnt, dinv, bufA, bufB);
    // layer 2
    k_gemm64b<true, false><<<NB_G, 256, 0, stream>>>(bufB, W2, b1, nullptr, bufA);
    k_gather3<<<NB_GA, 256, 0, stream>>>(epack, off, cnt, dinv, bufA, bufB);
    // layer 3
    k_gemm64b<true, false><<<NB_G, 256, 0, stream>>>(bufB, W3, b2, nullptr, bufA);
    k_gather3<<<NB_GA, 256, 0, stream>>>(epack, off, cnt, dinv, bufA, bufB);
    // scores = relu(bufB + b3) @ Wlin + blin
    k_gemm64b<true, true><<<NB_G, 256, 0, stream>>>(bufB, Wlin, b3, blin, bufA);

    // P = scores^T @ W4 (split-K over 261 chunks; Pp aliases dead bufB+epack)
    float* Pp = bufB;
    k_tgemm4<<<NB_T, 256, 0, stream>>>(bufA, W4, Pp);
    k_reduce2<<<512, 256, 0, stream>>>(Pp, P);

    // logits + log_softmax
    k_final<<<64, 256, 0, stream>>>(P, b4, W5, b5, out);
}